// Round 1
// baseline (483.596 us; speedup 1.0000x reference)
//
#include <hip/hip_runtime.h>
#include <hip/hip_bf16.h>
#include <math.h>

#define NTOK 100352          // 32*56*56
typedef __attribute__((ext_vector_type(8))) short short8_t;
typedef __attribute__((ext_vector_type(4))) float f32x4;

union I4S8 { int4 i; short h[8]; short8_t v; };

__device__ __forceinline__ short f2bf(float f) {
    union { float f; unsigned u; } x; x.f = f;
    unsigned r = x.u + 0x7FFFu + ((x.u >> 16) & 1u);
    return (short)(r >> 16);
}
__device__ __forceinline__ float bf2f(short s) {
    union { unsigned u; float f; } x; x.u = ((unsigned)(unsigned short)s) << 16;
    return x.f;
}

// ---------------- weight prep: f32 [K][N] -> bf16 [N][K] ----------------
__global__ void prep_weights(const float* __restrict__ qkv_w, const float* __restrict__ proj_w,
                             const float* __restrict__ fc1_w, const float* __restrict__ fc2_w,
                             short* __restrict__ wt) {
    int idx = blockIdx.x * 256 + threadIdx.x;
    const float* src; int K, N, base;
    if (idx < 49152)       { src = qkv_w;  K = 128; N = 384; base = 0; }
    else if (idx < 65536)  { src = proj_w; K = 128; N = 128; base = 49152; }
    else if (idx < 131072) { src = fc1_w;  K = 128; N = 512; base = 65536; }
    else                   { src = fc2_w;  K = 512; N = 128; base = 131072; }
    int local = idx - base;
    int n = local / K, k = local - n * K;
    wt[idx] = f2bf(src[k * N + n]);
}

// ---------------- LayerNorm (f32 in) -> bf16 out ----------------
__global__ __launch_bounds__(256) void ln_kernel(const float* __restrict__ in,
                                                 const float* __restrict__ g,
                                                 const float* __restrict__ b,
                                                 short* __restrict__ out) {
    int token = blockIdx.x * 4 + (threadIdx.x >> 6);
    int lane = threadIdx.x & 63;
    const float2 v = *reinterpret_cast<const float2*>(in + (size_t)token * 128 + lane * 2);
    float s = v.x + v.y;
    float sq = v.x * v.x + v.y * v.y;
    #pragma unroll
    for (int m = 32; m >= 1; m >>= 1) {
        s  += __shfl_xor(s, m);
        sq += __shfl_xor(sq, m);
    }
    float mean = s * (1.0f / 128.0f);
    float var = sq * (1.0f / 128.0f) - mean * mean;
    float rstd = rsqrtf(var + 1e-5f);
    float2 gg = *reinterpret_cast<const float2*>(g + lane * 2);
    float2 bb = *reinterpret_cast<const float2*>(b + lane * 2);
    float o0 = (v.x - mean) * rstd * gg.x + bb.x;
    float o1 = (v.y - mean) * rstd * gg.y + bb.y;
    unsigned pack = ((unsigned)(unsigned short)f2bf(o0)) |
                    (((unsigned)(unsigned short)f2bf(o1)) << 16);
    *reinterpret_cast<unsigned*>(out + (size_t)token * 128 + lane * 2) = pack;
}

// ---------------- GEMM: A bf16 [M][K] @ BT bf16 [N][K] ----------------
// EPI 0: store bf16 ; 1: +bias +res -> f32 ; 2: +bias, exact GELU -> bf16
template<int EPI>
__global__ __launch_bounds__(256) void gemm_kernel(const short* __restrict__ A,
                                                   const short* __restrict__ BT,
                                                   const float* __restrict__ bias,
                                                   const float* __restrict__ res,
                                                   void* __restrict__ out,
                                                   int N, int K) {
    __shared__ short As[64][136];
    __shared__ short Bs[64][136];
    const int m0 = blockIdx.x * 64;
    const int n0 = blockIdx.y * 64;
    const int tid = threadIdx.x;
    const int w = tid >> 6, lane = tid & 63;
    const int r = lane & 15, g = lane >> 4;

    f32x4 acc[4] = { {0.f,0.f,0.f,0.f}, {0.f,0.f,0.f,0.f},
                     {0.f,0.f,0.f,0.f}, {0.f,0.f,0.f,0.f} };

    for (int kc = 0; kc < K; kc += 128) {
        for (int i = tid; i < 1024; i += 256) {
            int row = i >> 4, seg = i & 15;
            int4 va = *reinterpret_cast<const int4*>(A + (size_t)(m0 + row) * K + kc + seg * 8);
            *reinterpret_cast<int4*>(&As[row][seg * 8]) = va;
            int4 vb = *reinterpret_cast<const int4*>(BT + (size_t)(n0 + row) * K + kc + seg * 8);
            *reinterpret_cast<int4*>(&Bs[row][seg * 8]) = vb;
        }
        __syncthreads();
        #pragma unroll
        for (int ks = 0; ks < 4; ++ks) {
            short8_t af = *reinterpret_cast<const short8_t*>(&As[w * 16 + r][ks * 32 + g * 8]);
            #pragma unroll
            for (int nt = 0; nt < 4; ++nt) {
                short8_t bfr = *reinterpret_cast<const short8_t*>(&Bs[nt * 16 + r][ks * 32 + g * 8]);
                acc[nt] = __builtin_amdgcn_mfma_f32_16x16x32_bf16(af, bfr, acc[nt], 0, 0, 0);
            }
        }
        __syncthreads();
    }

    #pragma unroll
    for (int nt = 0; nt < 4; ++nt) {
        int col = n0 + nt * 16 + r;
        float bv = (EPI != 0) ? bias[col] : 0.f;
        #pragma unroll
        for (int j = 0; j < 4; ++j) {
            int row = m0 + w * 16 + g * 4 + j;
            float v = acc[nt][j];
            if (EPI == 0) {
                ((short*)out)[(size_t)row * N + col] = f2bf(v);
            } else if (EPI == 1) {
                ((float*)out)[(size_t)row * N + col] = v + bv + res[(size_t)row * N + col];
            } else {
                float t = v + bv;
                float ge = 0.5f * t * (1.0f + erff(t * 0.70710678118654752f));
                ((short*)out)[(size_t)row * N + col] = f2bf(ge);
            }
        }
    }
}

// ---------------- fused window attention + LEPE ----------------
// grid (896, 2, 2): x = window (b*28 + w), y = head, z = type (0: 56x2, 1: 2x56)
__global__ __launch_bounds__(128) void attn_kernel(const short* __restrict__ qkv,
                                                   const float* __restrict__ cw0,
                                                   const float* __restrict__ cb0,
                                                   const float* __restrict__ cw1,
                                                   const float* __restrict__ cb1,
                                                   short* __restrict__ attout) {
    __shared__ float S[112][116];
    __shared__ short vT[32][120];
    __shared__ float invsum[112];

    const int win = blockIdx.x;
    const int head = blockIdx.y;
    const int type = blockIdx.z;
    const int b = win / 28;
    const int wdx = win - b * 28;
    const int tid = threadIdx.x;
    const int wv = tid >> 6, lane = tid & 63;
    const int r = lane & 15, g = lane >> 4;
    const int chb = type * 64 + head * 32;
    const float* cw = type ? cw1 : cw0;
    const float* cb = type ? cb1 : cb0;

    auto rowof = [&](int t) -> int {
        int l;
        if (type == 0) { int hs = t >> 1, wsp = t & 1; l = hs * 56 + wdx * 2 + wsp; }
        else           { int hs = (t >= 56) ? 1 : 0, wsp = t - hs * 56; l = (wdx * 2 + hs) * 56 + wsp; }
        return b * 3136 + l;
    };

    // stage V transposed: vT[d][tok]
    for (int i = tid; i < 448; i += 128) {
        int tt = i >> 2, seg = i & 3;
        int roww = rowof(tt);
        I4S8 u; u.i = *reinterpret_cast<const int4*>(qkv + (size_t)roww * 384 + 256 + chb + seg * 8);
        #pragma unroll
        for (int j = 0; j < 8; ++j) vT[seg * 8 + j][tt] = u.h[j];
    }

    // QK^T: B-frags (k) in registers, A-frags (q) per m-tile, from global
    short8_t kf[7];
    #pragma unroll
    for (int nt = 0; nt < 7; ++nt) {
        int roww = rowof(nt * 16 + r);
        kf[nt] = *reinterpret_cast<const short8_t*>(qkv + (size_t)roww * 384 + 128 + chb + g * 8);
    }
    const int mstart = (wv == 0) ? 0 : 4;
    const int mend   = (wv == 0) ? 4 : 7;
    const float scale = 0.17677669529663687f; // 1/sqrt(32)
    for (int mt = mstart; mt < mend; ++mt) {
        int roww = rowof(mt * 16 + r);
        short8_t af = *reinterpret_cast<const short8_t*>(qkv + (size_t)roww * 384 + chb + g * 8);
        f32x4 sa[7] = { {0.f,0.f,0.f,0.f},{0.f,0.f,0.f,0.f},{0.f,0.f,0.f,0.f},{0.f,0.f,0.f,0.f},
                        {0.f,0.f,0.f,0.f},{0.f,0.f,0.f,0.f},{0.f,0.f,0.f,0.f} };
        #pragma unroll
        for (int nt = 0; nt < 7; ++nt)
            sa[nt] = __builtin_amdgcn_mfma_f32_16x16x32_bf16(af, kf[nt], sa[nt], 0, 0, 0);
        #pragma unroll
        for (int nt = 0; nt < 7; ++nt)
            #pragma unroll
            for (int j = 0; j < 4; ++j)
                S[mt * 16 + g * 4 + j][nt * 16 + r] = sa[nt][j] * scale;
    }
    __syncthreads();

    // softmax per row, P (unnormalized exp) left in S, 1/sum deferred
    if (tid < 112) {
        float* srow = S[tid];
        float mx = -1e30f;
        for (int i = 0; i < 112; ++i) mx = fmaxf(mx, srow[i]);
        float sum = 0.f;
        for (int i = 0; i < 112; ++i) { float e = __expf(srow[i] - mx); srow[i] = e; sum += e; }
        invsum[tid] = 1.0f / sum;
    }
    __syncthreads();

    // PV + LEPE + store
    for (int idx = wv * 7; idx < wv * 7 + 7; ++idx) {
        int mt = idx >> 1, nt = idx & 1;
        int m0 = mt * 16, n0 = nt * 16;
        f32x4 acc = {0.f, 0.f, 0.f, 0.f};
        #pragma unroll
        for (int ks = 0; ks < 4; ++ks) {
            short8_t pa, vb;
            if (ks < 3 || g < 2) {
                int k0 = ks * 32 + g * 8;
                const float* sp = &S[m0 + r][k0];
                #pragma unroll
                for (int j = 0; j < 8; ++j) pa[j] = f2bf(sp[j]);
                vb = *reinterpret_cast<const short8_t*>(&vT[n0 + r][k0]);
            } else {
                #pragma unroll
                for (int j = 0; j < 8; ++j) { pa[j] = 0; vb[j] = 0; }
            }
            acc = __builtin_amdgcn_mfma_f32_16x16x32_bf16(pa, vb, acc, 0, 0, 0);
        }
        int d = n0 + r;               // hd index 0..31
        int cl = head * 32 + d;       // depthwise-conv channel 0..63
        float w9[9];
        #pragma unroll
        for (int j = 0; j < 9; ++j) w9[j] = cw[cl * 9 + j];
        float cbias = cb[cl];
        #pragma unroll
        for (int j = 0; j < 4; ++j) {
            int t = m0 + g * 4 + j;
            float v = acc[j] * invsum[t];
            int hs, wsp;
            if (type == 0) { hs = t >> 1; wsp = t & 1; }
            else           { hs = (t >= 56) ? 1 : 0; wsp = t - hs * 56; }
            float lp = cbias;
            #pragma unroll
            for (int ky = 0; ky < 3; ++ky) {
                int hh = hs + ky - 1;
                bool okh = (type == 0) ? (hh >= 0 && hh < 56) : (hh >= 0 && hh < 2);
                #pragma unroll
                for (int kx = 0; kx < 3; ++kx) {
                    int wwp = wsp + kx - 1;
                    bool okw = (type == 0) ? (wwp >= 0 && wwp < 2) : (wwp >= 0 && wwp < 56);
                    if (okh && okw) {
                        int tt = (type == 0) ? (hh * 2 + wwp) : (hh * 56 + wwp);
                        lp += w9[ky * 3 + kx] * bf2f(vT[d][tt]);
                    }
                }
            }
            v += lp;
            int roww = rowof(t);
            attout[(size_t)roww * 128 + chb + d] = f2bf(v);
        }
    }
}

extern "C" void kernel_launch(void* const* d_in, const int* in_sizes, int n_in,
                              void* d_out, int out_size, void* d_ws, size_t ws_size,
                              hipStream_t stream) {
    const float* x      = (const float*)d_in[0];
    const float* n1g    = (const float*)d_in[1];
    const float* n1b    = (const float*)d_in[2];
    const float* qkv_w  = (const float*)d_in[3];
    const float* proj_w = (const float*)d_in[4];
    const float* proj_b = (const float*)d_in[5];
    const float* cw0    = (const float*)d_in[6];
    const float* cb0    = (const float*)d_in[7];
    const float* cw1    = (const float*)d_in[8];
    const float* cb1    = (const float*)d_in[9];
    const float* n2g    = (const float*)d_in[10];
    const float* n2b    = (const float*)d_in[11];
    const float* fc1_w  = (const float*)d_in[12];
    const float* fc1_b  = (const float*)d_in[13];
    const float* fc2_w  = (const float*)d_in[14];
    const float* fc2_b  = (const float*)d_in[15];
    float* out = (float*)d_out;
    char* ws = (char*)d_ws;

    // workspace layout (bytes)
    short* img   = (short*)(ws + 0);            // [100352][128] bf16  (25,690,112)
    short* qkv   = (short*)(ws + 25690112);     // [100352][384] bf16  (77,070,336)
    short* att   = (short*)(ws + 102760448);    // [100352][128] bf16  (25,690,112)
    float* xres  = (float*)(ws + 128450560);    // [100352][128] f32   (51,380,224)
    short* wT    = (short*)(ws + 179830784);    // all weights bf16 [N][K] (393,216)
    short* wqkvT  = wT;
    short* wprojT = wT + 49152;
    short* wfc1T  = wT + 65536;
    short* wfc2T  = wT + 131072;
    short* hidden = qkv;   // [100352][512] bf16, aliases qkv+att (both dead by then)
    short* y2     = img;   // LN2 output aliases img

    prep_weights<<<768, 256, 0, stream>>>(qkv_w, proj_w, fc1_w, fc2_w, wT);
    ln_kernel<<<25088, 256, 0, stream>>>(x, n1g, n1b, img);
    gemm_kernel<0><<<dim3(1568, 6), 256, 0, stream>>>(img, wqkvT, nullptr, nullptr, qkv, 384, 128);
    attn_kernel<<<dim3(896, 2, 2), 128, 0, stream>>>(qkv, cw0, cb0, cw1, cb1, att);
    gemm_kernel<1><<<dim3(1568, 2), 256, 0, stream>>>(att, wprojT, proj_b, x, xres, 128, 128);
    ln_kernel<<<25088, 256, 0, stream>>>(xres, n2g, n2b, y2);
    gemm_kernel<2><<<dim3(1568, 8), 256, 0, stream>>>(y2, wfc1T, fc1_b, nullptr, hidden, 512, 128);
    gemm_kernel<1><<<dim3(1568, 2), 256, 0, stream>>>(hidden, wfc2T, fc2_b, xres, out, 128, 512);
}

// Round 2
// 383.584 us; speedup vs baseline: 1.2607x; 1.2607x over previous
//
#include <hip/hip_runtime.h>
#include <hip/hip_bf16.h>
#include <math.h>

#define NTOK 100352          // 32*56*56
typedef __attribute__((ext_vector_type(8))) short short8_t;
typedef __attribute__((ext_vector_type(4))) float f32x4;

union I4S8 { int4 i; short h[8]; short8_t v; };

__device__ __forceinline__ short f2bf(float f) {
    union { float f; unsigned u; } x; x.f = f;
    unsigned r = x.u + 0x7FFFu + ((x.u >> 16) & 1u);
    return (short)(r >> 16);
}
__device__ __forceinline__ float bf2f(short s) {
    union { unsigned u; float f; } x; x.u = ((unsigned)(unsigned short)s) << 16;
    return x.f;
}

// ---------------- weight prep: f32 [K][N] -> bf16 [N][K] ----------------
__global__ void prep_weights(const float* __restrict__ qkv_w, const float* __restrict__ proj_w,
                             const float* __restrict__ fc1_w, const float* __restrict__ fc2_w,
                             short* __restrict__ wt) {
    int idx = blockIdx.x * 256 + threadIdx.x;
    const float* src; int K, N, base;
    if (idx < 49152)       { src = qkv_w;  K = 128; N = 384; base = 0; }
    else if (idx < 65536)  { src = proj_w; K = 128; N = 128; base = 49152; }
    else if (idx < 131072) { src = fc1_w;  K = 128; N = 512; base = 65536; }
    else                   { src = fc2_w;  K = 512; N = 128; base = 131072; }
    int local = idx - base;
    int n = local / K, k = local - n * K;
    wt[idx] = f2bf(src[k * N + n]);
}

// ---------------- LayerNorm (f32 in) -> bf16 out ----------------
__global__ __launch_bounds__(256) void ln_kernel(const float* __restrict__ in,
                                                 const float* __restrict__ g,
                                                 const float* __restrict__ b,
                                                 short* __restrict__ out) {
    int token = blockIdx.x * 4 + (threadIdx.x >> 6);
    int lane = threadIdx.x & 63;
    const float2 v = *reinterpret_cast<const float2*>(in + (size_t)token * 128 + lane * 2);
    float s = v.x + v.y;
    float sq = v.x * v.x + v.y * v.y;
    #pragma unroll
    for (int m = 32; m >= 1; m >>= 1) {
        s  += __shfl_xor(s, m);
        sq += __shfl_xor(sq, m);
    }
    float mean = s * (1.0f / 128.0f);
    float var = sq * (1.0f / 128.0f) - mean * mean;
    float rstd = rsqrtf(var + 1e-5f);
    float2 gg = *reinterpret_cast<const float2*>(g + lane * 2);
    float2 bb = *reinterpret_cast<const float2*>(b + lane * 2);
    float o0 = (v.x - mean) * rstd * gg.x + bb.x;
    float o1 = (v.y - mean) * rstd * gg.y + bb.y;
    unsigned pack = ((unsigned)(unsigned short)f2bf(o0)) |
                    (((unsigned)(unsigned short)f2bf(o1)) << 16);
    *reinterpret_cast<unsigned*>(out + (size_t)token * 128 + lane * 2) = pack;
}

// ---------------- GEMM: A bf16 [M][K] @ BT bf16 [N][K] ----------------
// EPI 0: store bf16 ; 1: +bias +res -> f32 ; 2: +bias, exact GELU -> bf16
template<int EPI>
__global__ __launch_bounds__(256) void gemm_kernel(const short* __restrict__ A,
                                                   const short* __restrict__ BT,
                                                   const float* __restrict__ bias,
                                                   const float* __restrict__ res,
                                                   void* __restrict__ out,
                                                   int N, int K) {
    __shared__ short As[64][136];
    __shared__ short Bs[64][136];
    const int m0 = blockIdx.x * 64;
    const int n0 = blockIdx.y * 64;
    const int tid = threadIdx.x;
    const int w = tid >> 6, lane = tid & 63;
    const int r = lane & 15, g = lane >> 4;

    f32x4 acc[4] = { {0.f,0.f,0.f,0.f}, {0.f,0.f,0.f,0.f},
                     {0.f,0.f,0.f,0.f}, {0.f,0.f,0.f,0.f} };

    for (int kc = 0; kc < K; kc += 128) {
        for (int i = tid; i < 1024; i += 256) {
            int row = i >> 4, seg = i & 15;
            int4 va = *reinterpret_cast<const int4*>(A + (size_t)(m0 + row) * K + kc + seg * 8);
            *reinterpret_cast<int4*>(&As[row][seg * 8]) = va;
            int4 vb = *reinterpret_cast<const int4*>(BT + (size_t)(n0 + row) * K + kc + seg * 8);
            *reinterpret_cast<int4*>(&Bs[row][seg * 8]) = vb;
        }
        __syncthreads();
        #pragma unroll
        for (int ks = 0; ks < 4; ++ks) {
            short8_t af = *reinterpret_cast<const short8_t*>(&As[w * 16 + r][ks * 32 + g * 8]);
            #pragma unroll
            for (int nt = 0; nt < 4; ++nt) {
                short8_t bfr = *reinterpret_cast<const short8_t*>(&Bs[nt * 16 + r][ks * 32 + g * 8]);
                acc[nt] = __builtin_amdgcn_mfma_f32_16x16x32_bf16(af, bfr, acc[nt], 0, 0, 0);
            }
        }
        __syncthreads();
    }

    #pragma unroll
    for (int nt = 0; nt < 4; ++nt) {
        int col = n0 + nt * 16 + r;
        float bv = (EPI != 0) ? bias[col] : 0.f;
        #pragma unroll
        for (int j = 0; j < 4; ++j) {
            int row = m0 + w * 16 + g * 4 + j;
            float v = acc[nt][j];
            if (EPI == 0) {
                ((short*)out)[(size_t)row * N + col] = f2bf(v);
            } else if (EPI == 1) {
                ((float*)out)[(size_t)row * N + col] = v + bv + res[(size_t)row * N + col];
            } else {
                float t = v + bv;
                float ge = 0.5f * t * (1.0f + erff(t * 0.70710678118654752f));
                ((short*)out)[(size_t)row * N + col] = f2bf(ge);
            }
        }
    }
}

// ---------------- fused window attention + LEPE (wave-parallel softmax) ----------------
// grid (896, 2, 2): x = window (b*28 + w), y = head, z = type (0: 56x2, 1: 2x56)
// 256 threads = 4 waves. Wave w owns m-tiles {w, w+4} (w==3: just {3}).
// QK^T accs stay in registers; softmax in-register (shfl_xor over the 16-lane
// group that holds a fragment row); normalized P written bf16 to LDS; PV via MFMA.
__global__ __launch_bounds__(256) void attn_kernel(const short* __restrict__ qkv,
                                                   const float* __restrict__ cw0,
                                                   const float* __restrict__ cb0,
                                                   const float* __restrict__ cw1,
                                                   const float* __restrict__ cb1,
                                                   short* __restrict__ attout) {
    __shared__ short P[112][120];   // normalized probs, bf16
    __shared__ short vT[32][120];   // V transposed: vT[d][tok]

    const int win = blockIdx.x;
    const int head = blockIdx.y;
    const int type = blockIdx.z;
    const int b = win / 28;
    const int wdx = win - b * 28;
    const int tid = threadIdx.x;
    const int wv = tid >> 6, lane = tid & 63;
    const int r = lane & 15, g = lane >> 4;
    const int chb = type * 64 + head * 32;
    const float* cw = type ? cw1 : cw0;
    const float* cb = type ? cb1 : cb0;

    auto rowof = [&](int t) -> int {
        int l;
        if (type == 0) { int hs = t >> 1, wsp = t & 1; l = hs * 56 + wdx * 2 + wsp; }
        else           { int hs = (t >= 56) ? 1 : 0, wsp = t - hs * 56; l = (wdx * 2 + hs) * 56 + wsp; }
        return b * 3136 + l;
    };

    // stage V transposed: vT[d][tok]
    for (int i = tid; i < 448; i += 256) {
        int tt = i >> 2, seg = i & 3;
        int roww = rowof(tt);
        I4S8 u; u.i = *reinterpret_cast<const int4*>(qkv + (size_t)roww * 384 + 256 + chb + seg * 8);
        #pragma unroll
        for (int j = 0; j < 8; ++j) vT[seg * 8 + j][tt] = u.h[j];
    }

    // K-frags (B-operand) in registers, shared across this wave's m-tiles
    short8_t kf[7];
    #pragma unroll
    for (int nt = 0; nt < 7; ++nt) {
        int roww = rowof(nt * 16 + r);
        kf[nt] = *reinterpret_cast<const short8_t*>(qkv + (size_t)roww * 384 + 128 + chb + g * 8);
    }

    // QK^T into registers: sa[t][nt], t indexes this wave's m-tiles {wv, wv+4}
    f32x4 sa[2][7];
    #pragma unroll
    for (int t = 0; t < 2; ++t)
        #pragma unroll
        for (int nt = 0; nt < 7; ++nt)
            sa[t][nt] = (f32x4){0.f, 0.f, 0.f, 0.f};

    #pragma unroll
    for (int t = 0; t < 2; ++t) {
        int mt = wv + 4 * t;
        if (mt < 7) {
            int roww = rowof(mt * 16 + r);
            short8_t af = *reinterpret_cast<const short8_t*>(qkv + (size_t)roww * 384 + chb + g * 8);
            #pragma unroll
            for (int nt = 0; nt < 7; ++nt)
                sa[t][nt] = __builtin_amdgcn_mfma_f32_16x16x32_bf16(af, kf[nt], sa[t][nt], 0, 0, 0);
        }
    }

    // in-register softmax; rows of frag = g*4+j, cols nt*16+r (16-lane group)
    const float scale = 0.17677669529663687f; // 1/sqrt(32)
    #pragma unroll
    for (int t = 0; t < 2; ++t) {
        int mt = wv + 4 * t;
        if (mt < 7) {
            #pragma unroll
            for (int j = 0; j < 4; ++j) {
                float sv[7];
                float mx = -1e30f;
                #pragma unroll
                for (int nt = 0; nt < 7; ++nt) { sv[nt] = sa[t][nt][j] * scale; mx = fmaxf(mx, sv[nt]); }
                #pragma unroll
                for (int m = 8; m >= 1; m >>= 1) mx = fmaxf(mx, __shfl_xor(mx, m));
                float sum = 0.f;
                #pragma unroll
                for (int nt = 0; nt < 7; ++nt) { sv[nt] = __expf(sv[nt] - mx); sum += sv[nt]; }
                #pragma unroll
                for (int m = 8; m >= 1; m >>= 1) sum += __shfl_xor(sum, m);
                float inv = 1.0f / sum;
                int row = mt * 16 + g * 4 + j;
                #pragma unroll
                for (int nt = 0; nt < 7; ++nt)
                    P[row][nt * 16 + r] = f2bf(sv[nt] * inv);
            }
        }
    }
    __syncthreads();

    // PV + LEPE + store. 14 output frags (7 m-tiles x 2 d-tiles); wave w: w+4t
    #pragma unroll
    for (int t = 0; t < 4; ++t) {
        int idx = wv + 4 * t;
        if (idx < 14) {
            int mt = idx >> 1, nt = idx & 1;
            int m0 = mt * 16, n0 = nt * 16;
            f32x4 acc = {0.f, 0.f, 0.f, 0.f};
            #pragma unroll
            for (int ks = 0; ks < 4; ++ks) {
                short8_t pa, vb;
                if (ks < 3 || g < 2) {
                    int k0 = ks * 32 + g * 8;
                    pa = *reinterpret_cast<const short8_t*>(&P[m0 + r][k0]);
                    vb = *reinterpret_cast<const short8_t*>(&vT[n0 + r][k0]);
                } else {
                    #pragma unroll
                    for (int j = 0; j < 8; ++j) { pa[j] = 0; vb[j] = 0; }
                }
                acc = __builtin_amdgcn_mfma_f32_16x16x32_bf16(pa, vb, acc, 0, 0, 0);
            }
            int d = n0 + r;               // hd index 0..31
            int cl = head * 32 + d;       // depthwise-conv channel 0..63
            float w9[9];
            #pragma unroll
            for (int j = 0; j < 9; ++j) w9[j] = cw[cl * 9 + j];
            float cbias = cb[cl];
            #pragma unroll
            for (int j = 0; j < 4; ++j) {
                int tok = m0 + g * 4 + j;
                float v = acc[j];
                int hs, wsp;
                if (type == 0) { hs = tok >> 1; wsp = tok & 1; }
                else           { hs = (tok >= 56) ? 1 : 0; wsp = tok - hs * 56; }
                float lp = cbias;
                #pragma unroll
                for (int ky = 0; ky < 3; ++ky) {
                    int hh = hs + ky - 1;
                    bool okh = (type == 0) ? (hh >= 0 && hh < 56) : (hh >= 0 && hh < 2);
                    #pragma unroll
                    for (int kx = 0; kx < 3; ++kx) {
                        int wwp = wsp + kx - 1;
                        bool okw = (type == 0) ? (wwp >= 0 && wwp < 2) : (wwp >= 0 && wwp < 56);
                        if (okh && okw) {
                            int tt = (type == 0) ? (hh * 2 + wwp) : (hh * 56 + wwp);
                            lp += w9[ky * 3 + kx] * bf2f(vT[d][tt]);
                        }
                    }
                }
                v += lp;
                int roww = rowof(tok);
                attout[(size_t)roww * 128 + chb + d] = f2bf(v);
            }
        }
    }
}

extern "C" void kernel_launch(void* const* d_in, const int* in_sizes, int n_in,
                              void* d_out, int out_size, void* d_ws, size_t ws_size,
                              hipStream_t stream) {
    const float* x      = (const float*)d_in[0];
    const float* n1g    = (const float*)d_in[1];
    const float* n1b    = (const float*)d_in[2];
    const float* qkv_w  = (const float*)d_in[3];
    const float* proj_w = (const float*)d_in[4];
    const float* proj_b = (const float*)d_in[5];
    const float* cw0    = (const float*)d_in[6];
    const float* cb0    = (const float*)d_in[7];
    const float* cw1    = (const float*)d_in[8];
    const float* cb1    = (const float*)d_in[9];
    const float* n2g    = (const float*)d_in[10];
    const float* n2b    = (const float*)d_in[11];
    const float* fc1_w  = (const float*)d_in[12];
    const float* fc1_b  = (const float*)d_in[13];
    const float* fc2_w  = (const float*)d_in[14];
    const float* fc2_b  = (const float*)d_in[15];
    float* out = (float*)d_out;
    char* ws = (char*)d_ws;

    // workspace layout (bytes)
    short* img   = (short*)(ws + 0);            // [100352][128] bf16  (25,690,112)
    short* qkv   = (short*)(ws + 25690112);     // [100352][384] bf16  (77,070,336)
    short* att   = (short*)(ws + 102760448);    // [100352][128] bf16  (25,690,112)
    float* xres  = (float*)(ws + 128450560);    // [100352][128] f32   (51,380,224)
    short* wT    = (short*)(ws + 179830784);    // all weights bf16 [N][K] (393,216)
    short* wqkvT  = wT;
    short* wprojT = wT + 49152;
    short* wfc1T  = wT + 65536;
    short* wfc2T  = wT + 131072;
    short* hidden = qkv;   // [100352][512] bf16, aliases qkv+att (both dead by then)
    short* y2     = img;   // LN2 output aliases img

    prep_weights<<<768, 256, 0, stream>>>(qkv_w, proj_w, fc1_w, fc2_w, wT);
    ln_kernel<<<25088, 256, 0, stream>>>(x, n1g, n1b, img);
    gemm_kernel<0><<<dim3(1568, 6), 256, 0, stream>>>(img, wqkvT, nullptr, nullptr, qkv, 384, 128);
    attn_kernel<<<dim3(896, 2, 2), 256, 0, stream>>>(qkv, cw0, cb0, cw1, cb1, att);
    gemm_kernel<1><<<dim3(1568, 2), 256, 0, stream>>>(att, wprojT, proj_b, x, xres, 128, 128);
    ln_kernel<<<25088, 256, 0, stream>>>(xres, n2g, n2b, y2);
    gemm_kernel<2><<<dim3(1568, 8), 256, 0, stream>>>(y2, wfc1T, fc1_b, nullptr, hidden, 512, 128);
    gemm_kernel<1><<<dim3(1568, 2), 256, 0, stream>>>(hidden, wfc2T, fc2_b, xres, out, 128, 512);
}